// Round 1
// baseline (1242.824 us; speedup 1.0000x reference)
//
#include <hip/hip_runtime.h>
#include <hip/hip_bf16.h>

// Problem constants
#define Bb   2
#define Ss   2048
#define Dd   4096
#define Hh   32
#define HDd  128
#define Mm   4096   // Bb*Ss

using bf16 = __bf16;
typedef __bf16 bf16x8 __attribute__((ext_vector_type(8)));
typedef __bf16 bf16x4 __attribute__((ext_vector_type(4)));
typedef float  f32x4  __attribute__((ext_vector_type(4)));

__device__ __forceinline__ void gload_lds16(const void* g, void* l) {
  __builtin_amdgcn_global_load_lds(
      (const __attribute__((address_space(1))) void*)g,
      (__attribute__((address_space(3))) void*)l, 16, 0, 0);
}

// ---------------- fp32 -> bf16 cast, 8 elems/thread ----------------
__global__ __launch_bounds__(256) void cast_kernel(const float* __restrict__ in,
                                                   bf16* __restrict__ out, int n8) {
  int i = blockIdx.x * blockDim.x + threadIdx.x;
  int stride = gridDim.x * blockDim.x;
  for (; i < n8; i += stride) {
    float4 a = reinterpret_cast<const float4*>(in)[2 * i];
    float4 b = reinterpret_cast<const float4*>(in)[2 * i + 1];
    bf16x8 o;
    o[0] = (bf16)a.x; o[1] = (bf16)a.y; o[2] = (bf16)a.z; o[3] = (bf16)a.w;
    o[4] = (bf16)b.x; o[5] = (bf16)b.y; o[6] = (bf16)b.z; o[7] = (bf16)b.w;
    reinterpret_cast<bf16x8*>(out)[i] = o;
  }
}

// ---------------- GEMM: C = A * Bm^T  (4096^3, bf16 in, bf16/f32 out) -------
// m97 structure: 128x128 tile, BK=32, 4 waves (2x2 of 64x64), global_load_lds.
template <bool OUT_F32>
__global__ __launch_bounds__(256) void gemm_bt(const bf16* __restrict__ A,
                                               const bf16* __restrict__ Bm,
                                               void* __restrict__ Cv) {
  __shared__ bf16 As[128 * 32];
  __shared__ bf16 Bs[128 * 32];
  const int K = 4096, N = 4096;
  int m0 = (blockIdx.x >> 5) * 128;
  int n0 = (blockIdx.x & 31) * 128;
  int tid = threadIdx.x;
  int lane = tid & 63, wid = tid >> 6;
  int wr = wid >> 1, wc = wid & 1;
  int lq = lane & 15, lg = lane >> 4;
  f32x4 acc[4][4] = {};
  const long ldb = (long)K * 2;  // row stride bytes
  const char* Ag = (const char*)A + (long)(m0 + wid * 32 + (lane >> 2)) * ldb + (lane & 3) * 16;
  const char* Bg = (const char*)Bm + (long)(n0 + wid * 32 + (lane >> 2)) * ldb + (lane & 3) * 16;
  char* Al = (char*)As + wid * 2048;  // uniform per wave; HW adds lane*16
  char* Bl = (char*)Bs + wid * 2048;
  for (int k0 = 0; k0 < K; k0 += 32) {
    gload_lds16(Ag, Al);
    gload_lds16(Ag + 16 * ldb, Al + 1024);
    gload_lds16(Bg, Bl);
    gload_lds16(Bg + 16 * ldb, Bl + 1024);
    Ag += 64; Bg += 64;
    __syncthreads();
    bf16x8 af[4], bfr[4];
#pragma unroll
    for (int i = 0; i < 4; ++i)
      af[i] = *reinterpret_cast<const bf16x8*>(As + (wr * 64 + i * 16 + lq) * 32 + lg * 8);
#pragma unroll
    for (int j = 0; j < 4; ++j)
      bfr[j] = *reinterpret_cast<const bf16x8*>(Bs + (wc * 64 + j * 16 + lq) * 32 + lg * 8);
#pragma unroll
    for (int i = 0; i < 4; ++i)
#pragma unroll
      for (int j = 0; j < 4; ++j)
        acc[i][j] = __builtin_amdgcn_mfma_f32_16x16x32_bf16(af[i], bfr[j], acc[i][j], 0, 0, 0);
    __syncthreads();
  }
  int r0 = m0 + wr * 64 + lg * 4;
  int c0 = n0 + wc * 64 + lq;
  if (OUT_F32) {
    float* C = (float*)Cv;
#pragma unroll
    for (int i = 0; i < 4; ++i)
#pragma unroll
      for (int j = 0; j < 4; ++j)
#pragma unroll
        for (int r = 0; r < 4; ++r)
          C[(long)(r0 + i * 16 + r) * N + c0 + j * 16] = acc[i][j][r];
  } else {
    bf16* C = (bf16*)Cv;
#pragma unroll
    for (int i = 0; i < 4; ++i)
#pragma unroll
      for (int j = 0; j < 4; ++j)
#pragma unroll
        for (int r = 0; r < 4; ++r)
          C[(long)(r0 + i * 16 + r) * N + c0 + j * 16] = (bf16)acc[i][j][r];
  }
}

// ---------------- RoPE on Q and K in place (4 pairs / thread) ---------------
__global__ __launch_bounds__(256) void rope_qk(bf16* __restrict__ q, bf16* __restrict__ k,
                                               const float* __restrict__ fc,
                                               const float* __restrict__ fs) {
  int idx = blockIdx.x * blockDim.x + threadIdx.x;
  if (idx >= Mm * (Dd / 8)) return;
  int row = idx >> 9;        // Dd/8 = 512 chunks per row
  int chunk = idx & 511;
  int s = row & (Ss - 1);
  int e0 = chunk << 3;
  int i0 = (e0 & (HDd - 1)) >> 1;  // pair index within head, 4 consecutive
  float4 c4 = *reinterpret_cast<const float4*>(fc + s * 64 + i0);
  float4 s4 = *reinterpret_cast<const float4*>(fs + s * 64 + i0);
  float cc[4] = {c4.x, c4.y, c4.z, c4.w};
  float ss[4] = {s4.x, s4.y, s4.z, s4.w};
  long off = (long)row * Dd + e0;
  bf16x8 qv = *reinterpret_cast<bf16x8*>(q + off);
  bf16x8 kv = *reinterpret_cast<bf16x8*>(k + off);
  bf16x8 qo, ko;
#pragma unroll
  for (int p = 0; p < 4; ++p) {
    float qr = (float)qv[2 * p], qi = (float)qv[2 * p + 1];
    qo[2 * p]     = (bf16)(qr * cc[p] - qi * ss[p]);
    qo[2 * p + 1] = (bf16)(qr * ss[p] + qi * cc[p]);
    float kr = (float)kv[2 * p], ki = (float)kv[2 * p + 1];
    ko[2 * p]     = (bf16)(kr * cc[p] - ki * ss[p]);
    ko[2 * p + 1] = (bf16)(kr * ss[p] + ki * cc[p]);
  }
  *reinterpret_cast<bf16x8*>(q + off) = qo;
  *reinterpret_cast<bf16x8*>(k + off) = ko;
}

// ---------------- V transpose: (B,S,H,HD) -> (B,H,HD,S) ---------------------
__global__ __launch_bounds__(256) void transpose_v(const bf16* __restrict__ v,
                                                   bf16* __restrict__ vt) {
  __shared__ bf16 tile[64][72];
  int bid = blockIdx.x;
  int dt = bid & 1;           // HD/64
  int st = (bid >> 1) & 31;   // S/64
  int bh = bid >> 6;          // B*H
  int b = bh >> 5, h = bh & 31;
  int t = threadIdx.x;
  int lr = t >> 3;            // 0..31
  int lc = (t & 7) * 8;       // 0..56
  const bf16* src = v + ((long)b * Ss + st * 64) * Dd + h * HDd + dt * 64;
#pragma unroll
  for (int pass = 0; pass < 2; ++pass) {
    int srow = pass * 32 + lr;
    *reinterpret_cast<bf16x8*>(&tile[srow][lc]) =
        *reinterpret_cast<const bf16x8*>(src + (long)srow * Dd + lc);
  }
  __syncthreads();
  bf16* dst = vt + ((long)bh * HDd + dt * 64) * Ss + st * 64;
#pragma unroll
  for (int pass = 0; pass < 2; ++pass) {
    int drow = pass * 32 + lr;
    bf16x8 o;
#pragma unroll
    for (int j = 0; j < 8; ++j) o[j] = tile[lc + j][drow];
    *reinterpret_cast<bf16x8*>(dst + (long)drow * Ss + lc) = o;
  }
}

// ---------------- Flash attention (causal), bf16, swapped QK^T --------------
// grid: (B*H) * (S/64); block: 4 waves, each wave owns 16 q-rows, KBLK=64.
__global__ __launch_bounds__(256) void attn_fwd(const bf16* __restrict__ Q,
                                                const bf16* __restrict__ K,
                                                const bf16* __restrict__ Vt,
                                                bf16* __restrict__ O) {
  __shared__ bf16 Ks[64 * 128];   // [krow][hd], XOR-swizzled
  __shared__ bf16 Vs[128 * 64];   // [n][k],    XOR-swizzled
  __shared__ bf16 Ps[4][16][72];  // per-wave P, padded
  int bid = blockIdx.x;
  int bh = bid & 63;
  int qt = bid >> 6;
  int b = bh >> 5, h = bh & 31;
  int tid = threadIdx.x, lane = tid & 63, wid = tid >> 6;
  int lq = lane & 15, lg = lane >> 4;
  int q_glob = qt * 64 + wid * 16 + lq;
  // Q fragments hoisted into registers (B-operand of swapped QK^T)
  const bf16* qrow = Q + ((long)b * Ss + q_glob) * Dd + h * HDd;
  bf16x8 qf[4];
#pragma unroll
  for (int ks = 0; ks < 4; ++ks)
    qf[ks] = *reinterpret_cast<const bf16x8*>(qrow + ks * 32 + lg * 8);
  f32x4 acc_o[8] = {};
  float m_run = -1e30f, l_run = 0.f;
  const float scale2 = 0.088388347648318447f * 1.4426950408889634f;  // 1/sqrt(128)*log2(e)
  const char* kgb = (const char*)(K + (long)b * Ss * Dd + h * HDd);
  const char* vgb = (const char*)(Vt + (long)bh * HDd * Ss);
  char* Kl = (char*)Ks + wid * 16 * 256;
  char* Vl = (char*)Vs + wid * 32 * 128;
  int krow_st = wid * 16 + (lane >> 4);
  int kcb = (lane & 15) * 16;
  int vrow_st = wid * 32 + (lane >> 3);
  int vcb = (lane & 7) * 16;
  int nt = qt + 1;
  for (int t = 0; t < nt; ++t) {
    long kofs = (long)t * 64;
    // stage K tile (pre-swizzled global source; linear LDS dest)
#pragma unroll
    for (int inst = 0; inst < 4; ++inst) {
      int rr = krow_st + inst * 4;
      gload_lds16(kgb + (kofs + rr) * (Dd * 2) + (kcb ^ ((rr & 7) << 4)), Kl + inst * 1024);
    }
#pragma unroll
    for (int inst = 0; inst < 4; ++inst) {
      int rr = vrow_st + inst * 8;
      gload_lds16(vgb + (long)rr * (Ss * 2) + kofs * 2 + (vcb ^ ((rr & 7) << 4)),
                  Vl + inst * 1024);
    }
    __syncthreads();
    // swapped QK^T: S^T[k][q]
    f32x4 sc[4] = {};
#pragma unroll
    for (int ks = 0; ks < 4; ++ks)
#pragma unroll
      for (int m = 0; m < 4; ++m) {
        int krow = m * 16 + lq;
        int cb = (lg * 16 + ks * 64) ^ ((krow & 7) << 4);
        bf16x8 af = *reinterpret_cast<const bf16x8*>((const char*)Ks + krow * 256 + cb);
        sc[m] = __builtin_amdgcn_mfma_f32_16x16x32_bf16(af, qf[ks], sc[m], 0, 0, 0);
      }
    // online softmax in base-2; lane holds 16 k-values for q = lq
    float pv[16];
    float pmax = -1e30f;
    int kbase = t * 64 + lg * 4;
#pragma unroll
    for (int m = 0; m < 4; ++m)
#pragma unroll
      for (int r = 0; r < 4; ++r) {
        int kg_ = kbase + m * 16 + r;
        float v = sc[m][r] * scale2;
        v = (kg_ <= q_glob) ? v : -1e30f;
        pv[m * 4 + r] = v;
        pmax = fmaxf(pmax, v);
      }
    pmax = fmaxf(pmax, __shfl_xor(pmax, 16));
    pmax = fmaxf(pmax, __shfl_xor(pmax, 32));
    float m_new = fmaxf(m_run, pmax);
    float alpha = exp2f(m_run - m_new);
    float lsum = 0.f;
#pragma unroll
    for (int m = 0; m < 4; ++m) {
      bf16x4 pq;
#pragma unroll
      for (int r = 0; r < 4; ++r) {
        float p = exp2f(pv[m * 4 + r] - m_new);
        lsum += p;
        pq[r] = (bf16)p;
      }
      *reinterpret_cast<bf16x4*>(&Ps[wid][lq][m * 16 + lg * 4]) = pq;
    }
    lsum += __shfl_xor(lsum, 16);
    lsum += __shfl_xor(lsum, 32);
    l_run = l_run * alpha + lsum;
    m_run = m_new;
    // redistribute alpha to PV accumulator layout (q = 4*lg + r)
    float al[4];
#pragma unroll
    for (int r = 0; r < 4; ++r) al[r] = __shfl(alpha, (lane & 48) | (lg * 4 + r));
#pragma unroll
    for (int nf = 0; nf < 8; ++nf) {
      acc_o[nf][0] *= al[0]; acc_o[nf][1] *= al[1];
      acc_o[nf][2] *= al[2]; acc_o[nf][3] *= al[3];
    }
    // PV: O[q][n] += P[q][k] * V[k][n]
#pragma unroll
    for (int ks2 = 0; ks2 < 2; ++ks2) {
      bf16x8 pf = *reinterpret_cast<const bf16x8*>(&Ps[wid][lq][ks2 * 32 + lg * 8]);
#pragma unroll
      for (int nf = 0; nf < 8; ++nf) {
        int nrow = nf * 16 + lq;
        int cb = (lg * 16 + ks2 * 64) ^ ((nrow & 7) << 4);
        bf16x8 vf = *reinterpret_cast<const bf16x8*>((const char*)Vs + nrow * 128 + cb);
        acc_o[nf] = __builtin_amdgcn_mfma_f32_16x16x32_bf16(pf, vf, acc_o[nf], 0, 0, 0);
      }
    }
    __syncthreads();
  }
  float li[4];
#pragma unroll
  for (int r = 0; r < 4; ++r) li[r] = 1.0f / __shfl(l_run, (lane & 48) | (lg * 4 + r));
  bf16* orow = O + ((long)b * Ss + qt * 64 + wid * 16) * Dd + h * HDd;
#pragma unroll
  for (int nf = 0; nf < 8; ++nf)
#pragma unroll
    for (int r = 0; r < 4; ++r)
      orow[(long)(lg * 4 + r) * Dd + nf * 16 + lq] = (bf16)(acc_o[nf][r] * li[r]);
}

// ---------------------------------------------------------------------------
extern "C" void kernel_launch(void* const* d_in, const int* in_sizes, int n_in,
                              void* d_out, int out_size, void* d_ws, size_t ws_size,
                              hipStream_t stream) {
  const float* x    = (const float*)d_in[0];
  const float* fcos = (const float*)d_in[2];
  const float* fsin = (const float*)d_in[3];
  const float* wq   = (const float*)d_in[5];
  const float* wk   = (const float*)d_in[6];
  const float* wv   = (const float*)d_in[7];
  const float* wo   = (const float*)d_in[8];
  float* out = (float*)d_out;

  const size_t SZ = (size_t)Mm * Dd;  // 16,777,216 elems
  if (ws_size < 6 * SZ * sizeof(bf16)) return;  // need ~201 MB
  bf16* xb = (bf16*)d_ws;      // also reused as attention output (xb dead then)
  bf16* wb = xb + SZ;          // current weight (reused for wq/wk/wv/wo)
  bf16* qb = wb + SZ;
  bf16* kb = qb + SZ;
  bf16* vb = kb + SZ;
  bf16* vt = vb + SZ;
  bf16* ao = xb;

  const int n8 = (int)(SZ / 8);
  cast_kernel<<<dim3(2048), dim3(256), 0, stream>>>(x, xb, n8);

  cast_kernel<<<dim3(2048), dim3(256), 0, stream>>>(wq, wb, n8);
  gemm_bt<false><<<dim3(1024), dim3(256), 0, stream>>>(xb, wb, qb);
  cast_kernel<<<dim3(2048), dim3(256), 0, stream>>>(wk, wb, n8);
  gemm_bt<false><<<dim3(1024), dim3(256), 0, stream>>>(xb, wb, kb);
  cast_kernel<<<dim3(2048), dim3(256), 0, stream>>>(wv, wb, n8);
  gemm_bt<false><<<dim3(1024), dim3(256), 0, stream>>>(xb, wb, vb);

  rope_qk<<<dim3(8192), dim3(256), 0, stream>>>(qb, kb, fcos, fsin);
  transpose_v<<<dim3(4096), dim3(256), 0, stream>>>(vb, vt);

  attn_fwd<<<dim3(2048), dim3(256), 0, stream>>>(qb, kb, vt, ao);

  cast_kernel<<<dim3(2048), dim3(256), 0, stream>>>(wo, wb, n8);
  gemm_bt<true><<<dim3(1024), dim3(256), 0, stream>>>(ao, wb, out);
}

// Round 4
// 970.221 us; speedup vs baseline: 1.2810x; 1.2810x over previous
//
#include <hip/hip_runtime.h>
#include <hip/hip_bf16.h>

// Problem constants
#define Bb   2
#define Ss   2048
#define Dd   4096
#define Hh   32
#define HDd  128
#define Mm   4096   // Bb*Ss

using bf16 = __bf16;
typedef __bf16 bf16x8 __attribute__((ext_vector_type(8)));
typedef __bf16 bf16x4 __attribute__((ext_vector_type(4)));
typedef float  f32x4  __attribute__((ext_vector_type(4)));

__device__ __forceinline__ void gload_lds16(const void* g, void* l) {
  __builtin_amdgcn_global_load_lds(
      (const __attribute__((address_space(1))) void*)g,
      (__attribute__((address_space(3))) void*)l, 16, 0, 0);
}

// ---------------- fp32 -> bf16 cast, 8 elems/thread ----------------
__global__ __launch_bounds__(256) void cast_kernel(const float* __restrict__ in,
                                                   bf16* __restrict__ out, int n8) {
  int i = blockIdx.x * blockDim.x + threadIdx.x;
  int stride = gridDim.x * blockDim.x;
  for (; i < n8; i += stride) {
    float4 a = reinterpret_cast<const float4*>(in)[2 * i];
    float4 b = reinterpret_cast<const float4*>(in)[2 * i + 1];
    bf16x8 o;
    o[0] = (bf16)a.x; o[1] = (bf16)a.y; o[2] = (bf16)a.z; o[3] = (bf16)a.w;
    o[4] = (bf16)b.x; o[5] = (bf16)b.y; o[6] = (bf16)b.z; o[7] = (bf16)b.w;
    reinterpret_cast<bf16x8*>(out)[i] = o;
  }
}

// ---------------- GEMM 256x256 8-phase: C = A * Bm^T (4096^3) ---------------
// m201 template: BM=BN=256, BK=64, 8 waves (2Mx4N), 128KB LDS double-buffer,
// counted vmcnt (never 0 in loop), raw s_barrier, st-swizzled LDS, setprio.
template <bool OUT_F32>
__global__ __launch_bounds__(512, 2) void gemm256(const bf16* __restrict__ A,
                                                  const bf16* __restrict__ Bm,
                                                  void* __restrict__ Cv) {
  __shared__ char ldsb[131072];
  const int K = 4096, N = 4096;
  int bid = blockIdx.x;
  int swz = (bid & 7) * 32 + (bid >> 3);      // 256 % 8 == 0 -> bijective
  int m0 = (swz >> 4) << 8, n0 = (swz & 15) << 8;
  int tid = threadIdx.x, lane = tid & 63, w = tid >> 6;
  int wm = w >> 2, wn = w & 3;
  int lq = lane & 15, lg = lane >> 4;
  const long ldb = (long)K * 2;

  f32x4 acc[8][4] = {};

  // --- staging addresses: linear LDS dest, inverse-swizzled global source ---
  int srow = lane >> 3;                        // row&7 within each 8-row stripe
  int scol = ((lane & 7) * 16) ^ (srow << 4);  // pre-swizzled source column
  const char* agA = (const char*)A + (long)(m0 + w * 8 + srow) * ldb + scol;
  const char* agB = (const char*)Bm + (long)(n0 + w * 8 + srow) * ldb + scol;
  char* ldsw = ldsb + w * 1024;

  // --- fragment read addresses (swizzled on read: col ^= (row&7)<<4) --------
  int c0 = (lg * 16) ^ ((lq & 7) << 4);
  int c1 = c0 ^ 64;
  const char* aRd0 = ldsb + wm * 16384 + lq * 128 + c0;
  const char* aRd1 = ldsb + wm * 16384 + lq * 128 + c1;
  const char* bRd0 = ldsb + 32768 + (wn >> 1) * 16384 + ((wn & 1) * 64 + lq) * 128 + c0;
  const char* bRd1 = ldsb + 32768 + (wn >> 1) * 16384 + ((wn & 1) * 64 + lq) * 128 + c1;

  bf16x8 afrag[4], bfrag[8];

#define STAGE_A(buf, half, kt) do {                                         \
    const char* g_ = agA + (long)(half) * 128 * ldb + (long)(kt) * 128;     \
    char* l_ = ldsw + (buf) * 65536 + (half) * 16384;                       \
    gload_lds16(g_, l_);                                                    \
    gload_lds16(g_ + 64 * ldb, l_ + 8192);                                  \
  } while (0)
#define STAGE_B(buf, half, kt) do {                                         \
    const char* g_ = agB + (long)(half) * 128 * ldb + (long)(kt) * 128;     \
    char* l_ = ldsw + (buf) * 65536 + 32768 + (half) * 16384;               \
    gload_lds16(g_, l_);                                                    \
    gload_lds16(g_ + 64 * ldb, l_ + 8192);                                  \
  } while (0)
#define LDA(buf, q) do {                                                    \
    _Pragma("unroll") for (int ii = 0; ii < 2; ++ii) {                      \
      int ro = (buf) * 65536 + (2 * (q) + ii) * 2048;                       \
      afrag[ii * 2 + 0] = *(const bf16x8*)(aRd0 + ro);                      \
      afrag[ii * 2 + 1] = *(const bf16x8*)(aRd1 + ro);                      \
    }                                                                       \
  } while (0)
#define LDBF(buf) do {                                                      \
    _Pragma("unroll") for (int nj = 0; nj < 4; ++nj) {                      \
      int ro = (buf) * 65536 + nj * 2048;                                   \
      bfrag[nj * 2 + 0] = *(const bf16x8*)(bRd0 + ro);                      \
      bfrag[nj * 2 + 1] = *(const bf16x8*)(bRd1 + ro);                      \
    }                                                                       \
  } while (0)
#define MFMA_QUAD(q) do {                                                   \
    _Pragma("unroll") for (int kk = 0; kk < 2; ++kk)                        \
    _Pragma("unroll") for (int ii = 0; ii < 2; ++ii)                        \
    _Pragma("unroll") for (int nj = 0; nj < 4; ++nj)                        \
      acc[2 * (q) + ii][nj] = __builtin_amdgcn_mfma_f32_16x16x32_bf16(      \
          afrag[ii * 2 + kk], bfrag[nj * 2 + kk], acc[2 * (q) + ii][nj],    \
          0, 0, 0);                                                         \
  } while (0)
#define BAR_MFMA(q) do {                                                    \
    __builtin_amdgcn_s_barrier();                                           \
    asm volatile("s_waitcnt lgkmcnt(0)" ::: "memory");                      \
    __builtin_amdgcn_sched_barrier(0);                                      \
    __builtin_amdgcn_s_setprio(1);                                          \
    MFMA_QUAD(q);                                                           \
    __builtin_amdgcn_s_setprio(0);                                          \
    __builtin_amdgcn_s_barrier();                                           \
  } while (0)

  // prologue: tile0 (A+B) into buf0, tile1 B into buf1
  STAGE_A(0, 0, 0); STAGE_A(0, 1, 0);
  STAGE_B(0, 0, 0); STAGE_B(0, 1, 0);
  STAGE_B(1, 0, 1); STAGE_B(1, 1, 1);
  asm volatile("s_waitcnt vmcnt(0)" ::: "memory");
  __builtin_amdgcn_s_barrier();

  // 32 iterations x 2 K-tiles; stage schedule: ph1-2 buf1.A(t+1),
  // ph3-4 buf0.B(t+2), ph5-6 buf0.A(t+2), ph7-8 buf1.B(t+3).
  // vmcnt(4) at ph4 covers buf1.A (read ph5); at ph8 covers buf0.B/A (next ph1).
#pragma unroll 1
  for (int i = 0; i < 32; ++i) {
    int t = 2 * i;
    int t1 = (t + 1 < 64) ? t + 1 : 63;  // clamped: overflow stages are
    int t2 = (t + 2 < 64) ? t + 2 : 63;  // harmless rewrites of dead regions
    int t3 = (t + 3 < 64) ? t + 3 : 63;
    LDBF(0); LDA(0, 0); STAGE_A(1, 0, t1); BAR_MFMA(0);            // ph1
    LDA(0, 1);          STAGE_A(1, 1, t1); BAR_MFMA(1);            // ph2
    LDA(0, 2);          STAGE_B(0, 0, t2); BAR_MFMA(2);            // ph3
    LDA(0, 3);          STAGE_B(0, 1, t2);                         // ph4
    asm volatile("s_waitcnt vmcnt(4)" ::: "memory");
    BAR_MFMA(3);
    LDBF(1); LDA(1, 0); STAGE_A(0, 0, t2); BAR_MFMA(0);            // ph5
    LDA(1, 1);          STAGE_A(0, 1, t2); BAR_MFMA(1);            // ph6
    LDA(1, 2);          STAGE_B(1, 0, t3); BAR_MFMA(2);            // ph7
    LDA(1, 3);          STAGE_B(1, 1, t3);                         // ph8
    asm volatile("s_waitcnt vmcnt(4)" ::: "memory");
    BAR_MFMA(3);
  }

  // epilogue: C rows m0+wm*128+mi*16+lg*4+r, cols n0+wn*64+nj*16+lq
  long r0 = m0 + wm * 128 + lg * 4;
  int cb = n0 + wn * 64 + lq;
  if (OUT_F32) {
    float* C = (float*)Cv;
#pragma unroll
    for (int mi = 0; mi < 8; ++mi)
#pragma unroll
      for (int nj = 0; nj < 4; ++nj)
#pragma unroll
        for (int r = 0; r < 4; ++r)
          C[(r0 + mi * 16 + r) * (long)N + cb + nj * 16] = acc[mi][nj][r];
  } else {
    bf16* C = (bf16*)Cv;
#pragma unroll
    for (int mi = 0; mi < 8; ++mi)
#pragma unroll
      for (int nj = 0; nj < 4; ++nj)
#pragma unroll
        for (int r = 0; r < 4; ++r)
          C[(r0 + mi * 16 + r) * (long)N + cb + nj * 16] = (bf16)acc[mi][nj][r];
  }
#undef STAGE_A
#undef STAGE_B
#undef LDA
#undef LDBF
#undef MFMA_QUAD
#undef BAR_MFMA
}

// ---------------- RoPE on Q and K in place (4 pairs / thread) ---------------
__global__ __launch_bounds__(256) void rope_qk(bf16* __restrict__ q, bf16* __restrict__ k,
                                               const float* __restrict__ fc,
                                               const float* __restrict__ fs) {
  int idx = blockIdx.x * blockDim.x + threadIdx.x;
  if (idx >= Mm * (Dd / 8)) return;
  int row = idx >> 9;        // Dd/8 = 512 chunks per row
  int chunk = idx & 511;
  int s = row & (Ss - 1);
  int e0 = chunk << 3;
  int i0 = (e0 & (HDd - 1)) >> 1;  // pair index within head, 4 consecutive
  float4 c4 = *reinterpret_cast<const float4*>(fc + s * 64 + i0);
  float4 s4 = *reinterpret_cast<const float4*>(fs + s * 64 + i0);
  float cc[4] = {c4.x, c4.y, c4.z, c4.w};
  float ss[4] = {s4.x, s4.y, s4.z, s4.w};
  long off = (long)row * Dd + e0;
  bf16x8 qv = *reinterpret_cast<bf16x8*>(q + off);
  bf16x8 kv = *reinterpret_cast<bf16x8*>(k + off);
  bf16x8 qo, ko;
#pragma unroll
  for (int p = 0; p < 4; ++p) {
    float qr = (float)qv[2 * p], qi = (float)qv[2 * p + 1];
    qo[2 * p]     = (bf16)(qr * cc[p] - qi * ss[p]);
    qo[2 * p + 1] = (bf16)(qr * ss[p] + qi * cc[p]);
    float kr = (float)kv[2 * p], ki = (float)kv[2 * p + 1];
    ko[2 * p]     = (bf16)(kr * cc[p] - ki * ss[p]);
    ko[2 * p + 1] = (bf16)(kr * ss[p] + ki * cc[p]);
  }
  *reinterpret_cast<bf16x8*>(q + off) = qo;
  *reinterpret_cast<bf16x8*>(k + off) = ko;
}

// ---------------- V transpose: (B,S,H,HD) -> (B,H,HD,S) ---------------------
__global__ __launch_bounds__(256) void transpose_v(const bf16* __restrict__ v,
                                                   bf16* __restrict__ vt) {
  __shared__ bf16 tile[64][72];
  int bid = blockIdx.x;
  int dt = bid & 1;           // HD/64
  int st = (bid >> 1) & 31;   // S/64
  int bh = bid >> 6;          // B*H
  int b = bh >> 5, h = bh & 31;
  int t = threadIdx.x;
  int lr = t >> 3;            // 0..31
  int lc = (t & 7) * 8;       // 0..56
  const bf16* src = v + ((long)b * Ss + st * 64) * Dd + h * HDd + dt * 64;
#pragma unroll
  for (int pass = 0; pass < 2; ++pass) {
    int srow = pass * 32 + lr;
    *reinterpret_cast<bf16x8*>(&tile[srow][lc]) =
        *reinterpret_cast<const bf16x8*>(src + (long)srow * Dd + lc);
  }
  __syncthreads();
  bf16* dst = vt + ((long)bh * HDd + dt * 64) * Ss + st * 64;
#pragma unroll
  for (int pass = 0; pass < 2; ++pass) {
    int drow = pass * 32 + lr;
    bf16x8 o;
#pragma unroll
    for (int j = 0; j < 8; ++j) o[j] = tile[lc + j][drow];
    *reinterpret_cast<bf16x8*>(dst + (long)drow * Ss + lc) = o;
  }
}

// ---------------- Flash attention (causal), bf16, swapped QK^T --------------
// grid: (B*H) * (S/64); block: 4 waves, each wave owns 16 q-rows, KBLK=64.
__global__ __launch_bounds__(256) void attn_fwd(const bf16* __restrict__ Q,
                                                const bf16* __restrict__ K,
                                                const bf16* __restrict__ Vt,
                                                bf16* __restrict__ O) {
  __shared__ bf16 Ks[64 * 128];   // [krow][hd], XOR-swizzled
  __shared__ bf16 Vs[128 * 64];   // [n][k],    XOR-swizzled
  __shared__ bf16 Ps[4][16][72];  // per-wave P, padded
  int bid = blockIdx.x;
  int bh = bid & 63;
  int qt = bid >> 6;
  int b = bh >> 5, h = bh & 31;
  int tid = threadIdx.x, lane = tid & 63, wid = tid >> 6;
  int lq = lane & 15, lg = lane >> 4;
  int q_glob = qt * 64 + wid * 16 + lq;
  // Q fragments hoisted into registers (B-operand of swapped QK^T)
  const bf16* qrow = Q + ((long)b * Ss + q_glob) * Dd + h * HDd;
  bf16x8 qf[4];
#pragma unroll
  for (int ks = 0; ks < 4; ++ks)
    qf[ks] = *reinterpret_cast<const bf16x8*>(qrow + ks * 32 + lg * 8);
  f32x4 acc_o[8] = {};
  float m_run = -1e30f, l_run = 0.f;
  const float scale2 = 0.088388347648318447f * 1.4426950408889634f;  // 1/sqrt(128)*log2(e)
  const char* kgb = (const char*)(K + (long)b * Ss * Dd + h * HDd);
  const char* vgb = (const char*)(Vt + (long)bh * HDd * Ss);
  char* Kl = (char*)Ks + wid * 16 * 256;
  char* Vl = (char*)Vs + wid * 32 * 128;
  int krow_st = wid * 16 + (lane >> 4);
  int kcb = (lane & 15) * 16;
  int vrow_st = wid * 32 + (lane >> 3);
  int vcb = (lane & 7) * 16;
  int nt = qt + 1;
  for (int t = 0; t < nt; ++t) {
    long kofs = (long)t * 64;
    // stage K tile (pre-swizzled global source; linear LDS dest)
#pragma unroll
    for (int inst = 0; inst < 4; ++inst) {
      int rr = krow_st + inst * 4;
      gload_lds16(kgb + (kofs + rr) * (Dd * 2) + (kcb ^ ((rr & 7) << 4)), Kl + inst * 1024);
    }
#pragma unroll
    for (int inst = 0; inst < 4; ++inst) {
      int rr = vrow_st + inst * 8;
      gload_lds16(vgb + (long)rr * (Ss * 2) + kofs * 2 + (vcb ^ ((rr & 7) << 4)),
                  Vl + inst * 1024);
    }
    __syncthreads();
    // swapped QK^T: S^T[k][q]
    f32x4 sc[4] = {};
#pragma unroll
    for (int ks = 0; ks < 4; ++ks)
#pragma unroll
      for (int m = 0; m < 4; ++m) {
        int krow = m * 16 + lq;
        int cb = (lg * 16 + ks * 64) ^ ((krow & 7) << 4);
        bf16x8 af = *reinterpret_cast<const bf16x8*>((const char*)Ks + krow * 256 + cb);
        sc[m] = __builtin_amdgcn_mfma_f32_16x16x32_bf16(af, qf[ks], sc[m], 0, 0, 0);
      }
    // online softmax in base-2; lane holds 16 k-values for q = lq
    float pv[16];
    float pmax = -1e30f;
    int kbase = t * 64 + lg * 4;
#pragma unroll
    for (int m = 0; m < 4; ++m)
#pragma unroll
      for (int r = 0; r < 4; ++r) {
        int kg_ = kbase + m * 16 + r;
        float v = sc[m][r] * scale2;
        v = (kg_ <= q_glob) ? v : -1e30f;
        pv[m * 4 + r] = v;
        pmax = fmaxf(pmax, v);
      }
    pmax = fmaxf(pmax, __shfl_xor(pmax, 16));
    pmax = fmaxf(pmax, __shfl_xor(pmax, 32));
    float m_new = fmaxf(m_run, pmax);
    float alpha = exp2f(m_run - m_new);
    float lsum = 0.f;
#pragma unroll
    for (int m = 0; m < 4; ++m) {
      bf16x4 pq;
#pragma unroll
      for (int r = 0; r < 4; ++r) {
        float p = exp2f(pv[m * 4 + r] - m_new);
        lsum += p;
        pq[r] = (bf16)p;
      }
      *reinterpret_cast<bf16x4*>(&Ps[wid][lq][m * 16 + lg * 4]) = pq;
    }
    lsum += __shfl_xor(lsum, 16);
    lsum += __shfl_xor(lsum, 32);
    l_run = l_run * alpha + lsum;
    m_run = m_new;
    // redistribute alpha to PV accumulator layout (q = 4*lg + r)
    float al[4];
#pragma unroll
    for (int r = 0; r < 4; ++r) al[r] = __shfl(alpha, (lane & 48) | (lg * 4 + r));
#pragma unroll
    for (int nf = 0; nf < 8; ++nf) {
      acc_o[nf][0] *= al[0]; acc_o[nf][1] *= al[1];
      acc_o[nf][2] *= al[2]; acc_o[nf][3] *= al[3];
    }
    // PV: O[q][n] += P[q][k] * V[k][n]
#pragma unroll
    for (int ks2 = 0; ks2 < 2; ++ks2) {
      bf16x8 pf = *reinterpret_cast<const bf16x8*>(&Ps[wid][lq][ks2 * 32 + lg * 8]);
#pragma unroll
      for (int nf = 0; nf < 8; ++nf) {
        int nrow = nf * 16 + lq;
        int cb = (lg * 16 + ks2 * 64) ^ ((nrow & 7) << 4);
        bf16x8 vf = *reinterpret_cast<const bf16x8*>((const char*)Vs + nrow * 128 + cb);
        acc_o[nf] = __builtin_amdgcn_mfma_f32_16x16x32_bf16(pf, vf, acc_o[nf], 0, 0, 0);
      }
    }
    __syncthreads();
  }
  float li[4];
#pragma unroll
  for (int r = 0; r < 4; ++r) li[r] = 1.0f / __shfl(l_run, (lane & 48) | (lg * 4 + r));
  bf16* orow = O + ((long)b * Ss + qt * 64 + wid * 16) * Dd + h * HDd;
#pragma unroll
  for (int nf = 0; nf < 8; ++nf)
#pragma unroll
    for (int r = 0; r < 4; ++r)
      orow[(long)(lg * 4 + r) * Dd + nf * 16 + lq] = (bf16)(acc_o[nf][r] * li[r]);
}

// ---------------------------------------------------------------------------
extern "C" void kernel_launch(void* const* d_in, const int* in_sizes, int n_in,
                              void* d_out, int out_size, void* d_ws, size_t ws_size,
                              hipStream_t stream) {
  const float* x    = (const float*)d_in[0];
  const float* fcos = (const float*)d_in[2];
  const float* fsin = (const float*)d_in[3];
  const float* wq   = (const float*)d_in[5];
  const float* wk   = (const float*)d_in[6];
  const float* wv   = (const float*)d_in[7];
  const float* wo   = (const float*)d_in[8];
  float* out = (float*)d_out;

  const size_t SZ = (size_t)Mm * Dd;  // 16,777,216 elems
  if (ws_size < 6 * SZ * sizeof(bf16)) return;  // need ~201 MB
  bf16* xb = (bf16*)d_ws;      // also reused as attention output (xb dead then)
  bf16* wb = xb + SZ;          // current weight (reused for wq/wk/wv/wo)
  bf16* qb = wb + SZ;
  bf16* kb = qb + SZ;
  bf16* vb = kb + SZ;
  bf16* vt = vb + SZ;
  bf16* ao = xb;

  const int n8 = (int)(SZ / 8);
  cast_kernel<<<dim3(2048), dim3(256), 0, stream>>>(x, xb, n8);

  cast_kernel<<<dim3(2048), dim3(256), 0, stream>>>(wq, wb, n8);
  gemm256<false><<<dim3(256), dim3(512), 0, stream>>>(xb, wb, qb);
  cast_kernel<<<dim3(2048), dim3(256), 0, stream>>>(wk, wb, n8);
  gemm256<false><<<dim3(256), dim3(512), 0, stream>>>(xb, wb, kb);
  cast_kernel<<<dim3(2048), dim3(256), 0, stream>>>(wv, wb, n8);
  gemm256<false><<<dim3(256), dim3(512), 0, stream>>>(xb, wb, vb);

  rope_qk<<<dim3(8192), dim3(256), 0, stream>>>(qb, kb, fcos, fsin);
  transpose_v<<<dim3(4096), dim3(256), 0, stream>>>(vb, vt);

  attn_fwd<<<dim3(2048), dim3(256), 0, stream>>>(qb, kb, vt, ao);

  cast_kernel<<<dim3(2048), dim3(256), 0, stream>>>(wo, wb, n8);
  gemm256<true><<<dim3(256), dim3(512), 0, stream>>>(ao, wb, out);
}